// Round 14
// baseline (595.314 us; speedup 1.0000x reference)
//
#include <hip/hip_runtime.h>
#include <hip/hip_bf16.h>

#define NR 4096
#define DD 512
#define CAP 64   // max nnz per adjacency row (mean 20.5, P(>64) ~ 1e-22)

typedef __bf16 bf16x8 __attribute__((ext_vector_type(8)));
typedef float f32x4 __attribute__((ext_vector_type(4)));
typedef unsigned short u16;

#define AS_GLOBAL(p) ((const __attribute__((address_space(1))) unsigned int*)(p))
#define AS_LDS(p)    ((__attribute__((address_space(3))) unsigned int*)(p))

__device__ __forceinline__ u16 f2bf(float x) {
    __hip_bfloat16 h = __float2bfloat16(x);
    return *reinterpret_cast<u16*>(&h);
}

__device__ __forceinline__ float blo(unsigned u) { return __uint_as_float(u << 16); }
__device__ __forceinline__ float bhi(unsigned u) { return __uint_as_float(u & 0xffff0000u); }

// ---------------------------------------------------------------------------
// Kernel 1: row-normalize z1,z2 -> bf16, and d12[i] = zn1[i]·zn2[i] (fp32)
// ---------------------------------------------------------------------------
__global__ void norm_kernel(const float* z1, const float* z2,
                            u16* zn1, u16* zn2, float* d12) {
    const int row = blockIdx.x;
    const int t = threadIdx.x;           // 256 threads
    const float* r1 = z1 + (size_t)row * DD;
    const float* r2 = z2 + (size_t)row * DD;
    float a0 = r1[t], a1 = r1[t + 256];
    float b0 = r2[t], b1 = r2[t + 256];
    float ss1 = a0 * a0 + a1 * a1;
    float ss2 = b0 * b0 + b1 * b1;
    #pragma unroll
    for (int m = 1; m < 64; m <<= 1) {
        ss1 += __shfl_xor(ss1, m);
        ss2 += __shfl_xor(ss2, m);
    }
    __shared__ float s1s[4], s2s[4], ds[4];
    const int wid = t >> 6, lane = t & 63;
    if (lane == 0) { s1s[wid] = ss1; s2s[wid] = ss2; }
    __syncthreads();
    const float n1 = s1s[0] + s1s[1] + s1s[2] + s1s[3];
    const float n2 = s2s[0] + s2s[1] + s2s[2] + s2s[3];
    const float inv1 = 1.0f / fmaxf(sqrtf(n1), 1e-12f);
    const float inv2 = 1.0f / fmaxf(sqrtf(n2), 1e-12f);
    const float u0 = a0 * inv1, u1 = a1 * inv1;
    const float v0 = b0 * inv2, v1 = b1 * inv2;
    zn1[(size_t)row * DD + t]       = f2bf(u0);
    zn1[(size_t)row * DD + t + 256] = f2bf(u1);
    zn2[(size_t)row * DD + t]       = f2bf(v0);
    zn2[(size_t)row * DD + t + 256] = f2bf(v1);
    float dp = u0 * v0 + u1 * v1;
    #pragma unroll
    for (int m = 1; m < 64; m <<= 1) dp += __shfl_xor(dp, m);
    if (lane == 0) ds[wid] = dp;
    __syncthreads();
    if (t == 0) d12[row] = ds[0] + ds[1] + ds[2] + ds[3];
}

// ---------------------------------------------------------------------------
// Kernel 2 (FAT, 512-thread blocks): score tiles (8 waves, 64x32 each ->
// 32 AGPR/wave, no spill) + (sparsify->sparse) 8-wave quads.
// grid 3640: g=bid/7, r=bid%7.
//   r<4  -> score id=g*4+r in [0,2080): id<1024 S12 full grid (p1 rows/p3
//           cols); else triangles S11 (mode0,p0) / S22 (mode2,p2).
//   r>=4 -> sparse sid=g*3+(r-4), active <1536; block = 16 consecutive rows
//           (one m), wave = 2 rows. (Round-12 verbatim: the r13 2-deep
//           pipeline raised VGPR 64->72 and dropped occupancy 36->21%.)
// ---------------------------------------------------------------------------
__global__ __launch_bounds__(512, 3)
void fused_kernel(const u16* __restrict__ zn1, const u16* __restrict__ zn2,
                  const float* __restrict__ m0, const float* __restrict__ m1,
                  const float* __restrict__ m2, const float* __restrict__ m3,
                  const float* __restrict__ m4, const float* __restrict__ m5,
                  float* __restrict__ part, float* __restrict__ ms,
                  float* __restrict__ asum) {
    __shared__ u16 As[128 * 64];
    __shared__ u16 Bs[128 * 64];

    const int bid = blockIdx.x;
    const int tid = threadIdx.x;
    const int lane = tid & 63;

    const float C0 = 1.8033688011112042f;  // log2(e)/0.80
    const float C1 = 2.2542110013890054f;  // log2(e)/0.64
    const float C2 = 2.0037431123457825f;  // log2(e)/0.72

    const int g7 = bid / 7;
    const int r7 = bid - g7 * 7;

    if (r7 < 4) {
        // ================= SCORE PATH (8 waves, 64x32 per wave) =================
        const int id = g7 * 4 + r7;   // 0..2079
        int mode, by, bx;
        if (id < 1024) {
            mode = 1; by = id >> 5; bx = id & 31;
        } else {
            int k = id - 1024;
            mode = 0;
            if (k >= 528) { k -= 528; mode = 2; }
            int v = (int)((65.0f - sqrtf(4225.0f - 8.0f * (float)k)) * 0.5f);
            if (v < 0) v = 0; if (v > 31) v = 31;
            while (v < 31 && (v + 1) * 32 - ((v + 1) * v) / 2 <= k) v++;
            while (v > 0 && v * 32 - (v * (v - 1)) / 2 > k) v--;
            by = v;
            bx = by + (k - (by * 32 - (by * (by - 1)) / 2));
        }
        const int Ib = by * 128, Jb = bx * 128;
        const u16* Ag = (mode == 2) ? zn2 : zn1;
        const u16* Bg = (mode == 0) ? zn1 : zn2;
        const int p_row = mode;
        const int p_col = (mode == 1) ? 3 : mode;
        const bool do_cols = (mode == 1) || (bx != by);

        const int wid = tid >> 6;          // 0..7
        const int wm = wid >> 2;           // 0..1 (64-row half)
        const int wn = wid & 3;            // 0..3 (32-col quarter)
        const int quad = lane >> 4, lcol = lane & 15;

        f32x4 acc[4][2];
        #pragma unroll
        for (int a = 0; a < 4; a++)
            #pragma unroll
            for (int b = 0; b < 2; b++)
                acc[a][b] = (f32x4){0.f, 0.f, 0.f, 0.f};

        // 2 staging chunks per wave per buffer (16 chunks of 1 KB each)
        unsigned oA[2], oB[2];
        #pragma unroll
        for (int cc = 0; cc < 2; cc++) {
            const int ch = cc * 8 + wid;
            const int p = ch * 64 + lane;
            const int r = p >> 3;
            const int kb = (p & 7) ^ (r & 7);
            oA[cc] = (unsigned)((Ib + r) * DD + kb * 8);
            oB[cc] = (unsigned)((Jb + r) * DD + kb * 8);
        }

        for (int k0 = 0; k0 < DD; k0 += 64) {
            __syncthreads();
            #pragma unroll
            for (int cc = 0; cc < 2; cc++) {
                const unsigned lo = (unsigned)(cc * 8 + wid) * 1024u;
                __builtin_amdgcn_global_load_lds(AS_GLOBAL(Ag + oA[cc] + k0),
                                                 AS_LDS((char*)As + lo), 16, 0, 0);
                __builtin_amdgcn_global_load_lds(AS_GLOBAL(Bg + oB[cc] + k0),
                                                 AS_LDS((char*)Bs + lo), 16, 0, 0);
            }
            __syncthreads();
            #pragma unroll
            for (int kk = 0; kk < 64; kk += 32) {
                const int kbb = (kk >> 3) + quad;
                bf16x8 a[4], b[2];
                #pragma unroll
                for (int i = 0; i < 4; i++) {
                    const int ra = wm * 64 + i * 16 + lcol;
                    a[i] = *(const bf16x8*)&As[ra * 64 + ((kbb ^ (ra & 7)) * 8)];
                }
                #pragma unroll
                for (int i = 0; i < 2; i++) {
                    const int rb = wn * 32 + i * 16 + lcol;
                    b[i] = *(const bf16x8*)&Bs[rb * 64 + ((kbb ^ (rb & 7)) * 8)];
                }
                #pragma unroll
                for (int mi = 0; mi < 4; mi++)
                    #pragma unroll
                    for (int ni = 0; ni < 2; ni++)
                        acc[mi][ni] = __builtin_amdgcn_mfma_f32_16x16x32_bf16(a[mi], b[ni], acc[mi][ni], 0, 0, 0);
            }
        }

        // epilogue reuses As: sRow[4][3][128] (1536 f) + sCol[2][3][128] (768 f)
        __syncthreads();
        float* eb = (float*)As;
        float* sRow = eb;
        float* sCol = eb + 1536;

        float colacc[3][2];
        #pragma unroll
        for (int t = 0; t < 3; t++)
            #pragma unroll
            for (int ni = 0; ni < 2; ni++) colacc[t][ni] = 0.f;

        #pragma unroll
        for (int mi = 0; mi < 4; mi++) {
            #pragma unroll
            for (int reg = 0; reg < 4; reg++) {
                float p0 = 0.f, p1 = 0.f, p2 = 0.f;
                #pragma unroll
                for (int ni = 0; ni < 2; ni++) {
                    const float s = acc[mi][ni][reg];
                    const float e0 = __builtin_amdgcn_exp2f(s * C0);
                    const float e1 = __builtin_amdgcn_exp2f(s * C1);
                    const float e2 = __builtin_amdgcn_exp2f(s * C2);
                    p0 += e0; p1 += e1; p2 += e2;
                    colacc[0][ni] += e0; colacc[1][ni] += e1; colacc[2][ni] += e2;
                }
                #pragma unroll
                for (int msk = 1; msk < 16; msk <<= 1) {
                    p0 += __shfl_xor(p0, msk);
                    p1 += __shfl_xor(p1, msk);
                    p2 += __shfl_xor(p2, msk);
                }
                if (lcol == 0) {
                    const int r = wm * 64 + mi * 16 + quad * 4 + reg;
                    sRow[(wn * 3 + 0) * 128 + r] = p0;
                    sRow[(wn * 3 + 1) * 128 + r] = p1;
                    sRow[(wn * 3 + 2) * 128 + r] = p2;
                }
            }
        }
        #pragma unroll
        for (int t = 0; t < 3; t++) {
            #pragma unroll
            for (int ni = 0; ni < 2; ni++) {
                float v = colacc[t][ni];
                v += __shfl_xor(v, 16); v += __shfl_xor(v, 32);
                if (quad == 0) sCol[(wm * 3 + t) * 128 + wn * 32 + ni * 16 + lcol] = v;
            }
        }
        __syncthreads();
        if (tid < 128) {
            const int i = Ib + tid;
            #pragma unroll
            for (int t = 0; t < 3; t++) {
                const float v = sRow[(0 * 3 + t) * 128 + tid] + sRow[(1 * 3 + t) * 128 + tid]
                              + sRow[(2 * 3 + t) * 128 + tid] + sRow[(3 * 3 + t) * 128 + tid];
                part[(((size_t)p_row * 3 + t) * 32 + bx) * NR + i] = v;
            }
        } else if (tid < 256 && do_cols) {
            const int c = tid - 128;
            const int j = Jb + c;
            #pragma unroll
            for (int t = 0; t < 3; t++) {
                const float v = sCol[(0 * 3 + t) * 128 + c] + sCol[(1 * 3 + t) * 128 + c];
                part[(((size_t)p_col * 3 + t) * 32 + by) * NR + j] = v;
            }
        }
    } else {
        // ===== SPARSIFY + SPARSE PATH (8 waves x 2 rows; no barrier) =====
        const int sid = g7 * 3 + (r7 - 4);     // [0, 1560)
        if (sid >= 1536) return;
        const int widx = tid >> 6;             // 0..7
        const int grp = lane >> 4;
        const int l = lane & 15;
        const int wbase = sid * 16 + widx * 2; // even, block spans 16 rows, one m
        const int m = wbase >> 12;
        const int i0 = wbase & (NR - 1);

        const float* M = (m == 0) ? m0 : (m == 1) ? m1 : (m == 2) ? m2
                       : (m == 3) ? m3 : (m == 4) ? m4 : m5;
        const float4* p0 = (const float4*)(M + (size_t)i0 * NR) + lane;
        const float4* p1 = (const float4*)(M + (size_t)(i0 + 1) * NR) + lane;
        unsigned long long mask0 = 0ull, mask1 = 0ull;
        #pragma unroll
        for (int t = 0; t < 16; t++) {
            const float4 va = p0[t * 64];
            const float4 vb = p1[t * 64];
            mask0 |= (unsigned long long)((va.x != 0.f ? 1u : 0u)
                   | (va.y != 0.f ? 2u : 0u)
                   | (va.z != 0.f ? 4u : 0u)
                   | (va.w != 0.f ? 8u : 0u)) << (t * 4);
            mask1 |= (unsigned long long)((vb.x != 0.f ? 1u : 0u)
                   | (vb.y != 0.f ? 2u : 0u)
                   | (vb.z != 0.f ? 4u : 0u)
                   | (vb.w != 0.f ? 8u : 0u)) << (t * 4);
        }
        const int n0 = __popcll(mask0), n1 = __popcll(mask1);
        int off0 = n0, off1 = n1;
        #pragma unroll
        for (int d = 1; d < 64; d <<= 1) {
            const int t0 = __shfl_up(off0, d);
            const int t1 = __shfl_up(off1, d);
            if (lane >= d) { off0 += t0; off1 += t1; }
        }
        const int total0 = __shfl(off0, 63), total1 = __shfl(off1, 63);
        int* lidx0 = ((int*)As) + widx * 128;
        int* lidx1 = lidx0 + 64;
        int pos = off0 - n0;
        unsigned long long mm = mask0;
        while (mm) {
            const int b = __ffsll(mm) - 1;
            mm &= mm - 1;
            if (pos < CAP) lidx0[pos] = ((b >> 2) * 64 + lane) * 4 + (b & 3);
            pos++;
        }
        pos = off1 - n1;
        mm = mask1;
        while (mm) {
            const int b = __ffsll(mm) - 1;
            mm &= mm - 1;
            if (pos < CAP) lidx1[pos] = ((b >> 2) * 64 + lane) * 4 + (b & 3);
            pos++;
        }
        if (lane == 63) {
            asum[(size_t)m * NR + i0]     = (float)total0;
            asum[(size_t)m * NR + i0 + 1] = (float)total1;
        }
        const int cnt0 = min(total0, CAP), cnt1 = min(total1, CAP);
        // wave-private LDS: compiler inserts lgkmcnt before these reads
        const int jreg0 = lidx0[lane];
        const int jreg1 = lidx1[lane];

        int nslot; int slot[3]; float coef[3];
        switch (m) {
            case 0: nslot = 2; slot[0] = 0; coef[0] = C0; slot[1] = 3; coef[1] = C1; break;
            case 1: nslot = 2; slot[0] = 1; coef[0] = C0; slot[1] = 4; coef[1] = C2; break;
            case 2: nslot = 1; slot[0] = 2; coef[0] = C0; break;
            case 3: nslot = 1; slot[0] = 0; coef[0] = C0; break;
            case 4: nslot = 1; slot[0] = 1; coef[0] = C0; break;
            default: nslot = 3; slot[0] = 2; coef[0] = C0; slot[1] = 3; coef[1] = C1;
                     slot[2] = 4; coef[2] = C2; break;
        }

        const u16* A = (m < 3) ? zn1 : zn2;

        for (int rr = 0; rr < 2; rr++) {
            const int i = i0 + rr;
            const int cnt = rr ? cnt1 : cnt0;
            const int jreg = rr ? jreg1 : jreg0;

            unsigned au[16];
            {
                const uint4* ap = (const uint4*)(A + (size_t)i * DD) + l * 4;
                #pragma unroll
                for (int t = 0; t < 4; t++) {
                    const uint4 r = ap[t];
                    au[t * 4 + 0] = r.x; au[t * 4 + 1] = r.y;
                    au[t * 4 + 2] = r.z; au[t * 4 + 3] = r.w;
                }
            }

            float acc[3][2] = {{0.f, 0.f}, {0.f, 0.f}, {0.f, 0.f}};

            for (int q0 = 0; q0 < cnt; q0 += 4) {
                const int q = q0 + grp;
                const bool valid = q < cnt;
                const int j = __shfl(jreg, valid ? q : 0);

                const uint4* pj1 = (const uint4*)(zn1 + (size_t)j * DD) + l * 4;
                const uint4* pj2 = (const uint4*)(zn2 + (size_t)j * DD) + l * 4;
                uint4 r1[4], r2[4];
                #pragma unroll
                for (int t = 0; t < 4; t++) { r1[t] = pj1[t]; r2[t] = pj2[t]; }

                float s10 = 0.f, s11 = 0.f, s20 = 0.f, s21 = 0.f;
                #pragma unroll
                for (int t = 0; t < 4; t++) {
                    const unsigned* u1 = (const unsigned*)&r1[t];
                    const unsigned* u2 = (const unsigned*)&r2[t];
                    #pragma unroll
                    for (int qd = 0; qd < 4; qd++) {
                        const unsigned aw = au[t * 4 + qd];
                        const float alo = blo(aw), ahi = bhi(aw);
                        s10 += alo * blo(u1[qd]); s11 += ahi * bhi(u1[qd]);
                        s20 += alo * blo(u2[qd]); s21 += ahi * bhi(u2[qd]);
                    }
                }
                float d1 = s10 + s11, d2 = s20 + s21;
                #pragma unroll
                for (int msk = 1; msk < 16; msk <<= 1) {
                    d1 += __shfl_xor(d1, msk);
                    d2 += __shfl_xor(d2, msk);
                }
                const float e1 = (m < 3) ? d1 : d2;
                const float e2 = (m < 3) ? d2 : d1;
                if (valid) {
                    for (int s = 0; s < nslot; s++) {
                        acc[s][0] += __builtin_amdgcn_exp2f(e1 * coef[s]);
                        acc[s][1] += __builtin_amdgcn_exp2f(e2 * coef[s]);
                    }
                }
            }

            #pragma unroll
            for (int s = 0; s < 3; s++) {
                #pragma unroll
                for (int h = 0; h < 2; h++) {
                    float v = acc[s][h];
                    v += __shfl_xor(v, 16);
                    v += __shfl_xor(v, 32);
                    acc[s][h] = v;
                }
            }
            if (lane == 0) {
                const int pb = (m < 3) ? 0 : 2;
                for (int s = 0; s < nslot; s++) {
                    ms[((pb)     * 5 + slot[s]) * NR + i] = acc[s][0];
                    ms[((pb + 1) * 5 + slot[s]) * NR + i] = acc[s][1];
                }
            }
        }
    }
}

// ---------------------------------------------------------------------------
// Kernel 3: per-row loss terms (inline 32-slot reduce of part), block-reduced
// -> pout[16][13]
// ---------------------------------------------------------------------------
__global__ __launch_bounds__(256)
void finalize1_kernel(const float* __restrict__ part, const float* __restrict__ ms,
                      const float* __restrict__ asum, const float* __restrict__ d12,
                      float* __restrict__ pout) {
    const int t = threadIdx.x;
    const int i = blockIdx.x * 256 + t;
    const int tA[5] = {0, 0, 0, 1, 2};
    const int kA[5] = {0, 1, 2, 3, 4};
    const int aA[5] = {0, 1, 2, 0, 1};
    const int aB[5] = {3, 4, 5, 5, 5};
    const float it[3] = {1.25f, 1.5625f, 1.3888888888888888f};
    const float e1t[3] = {expf(1.25f), expf(1.5625f), expf(1.3888888888888888f)};

    const float d = d12[i];
    float ed[3];
    ed[0] = __expf(d * it[0]); ed[1] = __expf(d * it[1]); ed[2] = __expf(d * it[2]);
    float R[4][3], M[4][5], A6[6];
    #pragma unroll
    for (int p = 0; p < 4; p++) {
        #pragma unroll
        for (int tt = 0; tt < 3; tt++) {
            const float* base = part + (((size_t)p * 3 + tt) * 32) * NR + i;
            float s = 0.f;
            #pragma unroll
            for (int k = 0; k < 32; k++) s += base[(size_t)k * NR];
            R[p][tt] = s;
        }
        #pragma unroll
        for (int k = 0; k < 5; k++) M[p][k] = ms[(p * 5 + k) * NR + i];
    }
    #pragma unroll
    for (int a = 0; a < 6; a++) A6[a] = asum[a * NR + i];

    float vals[13];
    #pragma unroll
    for (int c = 0; c < 5; c++) {
        const int tt = tA[c], k = kA[c];
        float pos = ed[tt] + M[0][k] + M[1][k];
        float den = R[0][tt] + R[1][tt] - e1t[tt];
        float cnt = 2.f * A6[aA[c]] + 1.f;
        vals[c] = __logf(pos / den) / cnt;
        pos = ed[tt] + M[2][k] + M[3][k];
        den = R[2][tt] + R[3][tt] - e1t[tt];
        cnt = 2.f * A6[aB[c]] + 1.f;
        vals[5 + c] = __logf(pos / den) / cnt;
    }
    vals[10] = A6[0]; vals[11] = A6[1]; vals[12] = A6[2];

    __shared__ float red[256];
    for (int q = 0; q < 13; q++) {
        red[t] = vals[q];
        __syncthreads();
        for (int s = 128; s > 0; s >>= 1) {
            if (t < s) red[t] += red[t + s];
            __syncthreads();
        }
        if (t == 0) pout[blockIdx.x * 13 + q] = red[0];
        __syncthreads();
    }
}

// ---------------------------------------------------------------------------
// Kernel 4: combine the 16 partials -> final scalar
// ---------------------------------------------------------------------------
__global__ void finalize2_kernel(const float* pout, float* out) {
    if (threadIdx.x == 0) {
        float tot[13];
        #pragma unroll
        for (int q = 0; q < 13; q++) tot[q] = 0.f;
        for (int b = 0; b < 16; b++)
            #pragma unroll
            for (int q = 0; q < 13; q++) tot[q] += pout[b * 13 + q];
        float Ac[5], Bc[5];
        #pragma unroll
        for (int c = 0; c < 5; c++) {
            Ac[c] = -tot[c] / (float)NR;
            Bc[c] = -tot[5 + c] / (float)NR;
        }
        const float ALPHA = 0.55f, BETA = 0.4f;
        const float Lc  = ALPHA * Ac[0] + BETA * Bc[0];
        const float Lm  = ALPHA * Ac[1] + BETA * Bc[1];
        const float Lf  = ALPHA * Ac[2] + BETA * Bc[2];
        const float Lcf = ALPHA * Ac[3] + BETA * Bc[3];
        const float Lmf = ALPHA * Ac[4] + BETA * Bc[4];
        const float scs = tot[10], sms = tot[11], sfs = tot[12];
        const float tot_info = scs + sms + sfs + 1e-8f;
        out[0] = (scs * Lc + sms * Lm + sfs * Lf) / tot_info + 0.2f * (Lcf + Lmf);
    }
}

extern "C" void kernel_launch(void* const* d_in, const int* in_sizes, int n_in,
                              void* d_out, int out_size, void* d_ws, size_t ws_size,
                              hipStream_t stream) {
    const float* z1  = (const float*)d_in[0];
    const float* z2  = (const float*)d_in[1];
    const float* ac  = (const float*)d_in[2];
    const float* am  = (const float*)d_in[3];
    const float* af  = (const float*)d_in[4];
    const float* aca = (const float*)d_in[5];
    const float* ama = (const float*)d_in[6];
    const float* afa = (const float*)d_in[7];

    float* ws   = (float*)d_ws;
    float* rs   = ws;                            // 12*NR (unused now, kept for layout)
    float* ms   = rs + 12 * NR;                  // 20*NR
    float* asum = ms + 20 * NR;                  // 6*NR
    float* d12  = asum + 6 * NR;                 // NR
    u16* zn1 = (u16*)(d12 + NR);                 // NR*DD bf16
    u16* zn2 = zn1 + (size_t)NR * DD;
    float* part = (float*)(zn2 + (size_t)NR * DD);   // 12*32*NR
    float* pout = part + (size_t)12 * 32 * NR;       // 16*13

    norm_kernel<<<NR, 256, 0, stream>>>(z1, z2, zn1, zn2, d12);
    fused_kernel<<<3640, 512, 0, stream>>>(zn1, zn2, ac, am, af, aca, ama, afa,
                                           part, ms, asum);
    finalize1_kernel<<<16, 256, 0, stream>>>(part, ms, asum, d12, pout);
    finalize2_kernel<<<1, 64, 0, stream>>>(pout, (float*)d_out);
}

// Round 15
// 486.510 us; speedup vs baseline: 1.2236x; 1.2236x over previous
//
#include <hip/hip_runtime.h>
#include <hip/hip_bf16.h>

#define NR 4096
#define DD 512
#define CAP 64   // max nnz per adjacency row (mean 20.5, P(>64) ~ 1e-22)

typedef __bf16 bf16x8 __attribute__((ext_vector_type(8)));
typedef float f32x4 __attribute__((ext_vector_type(4)));
typedef unsigned short u16;

#define AS_GLOBAL(p) ((const __attribute__((address_space(1))) unsigned int*)(p))
#define AS_LDS(p)    ((__attribute__((address_space(3))) unsigned int*)(p))

__device__ __forceinline__ u16 f2bf(float x) {
    __hip_bfloat16 h = __float2bfloat16(x);
    return *reinterpret_cast<u16*>(&h);
}

__device__ __forceinline__ float blo(unsigned u) { return __uint_as_float(u << 16); }
__device__ __forceinline__ float bhi(unsigned u) { return __uint_as_float(u & 0xffff0000u); }

// ---------------------------------------------------------------------------
// Kernel 1: row-normalize z1,z2 -> bf16, and d12[i] = zn1[i]·zn2[i] (fp32)
// ---------------------------------------------------------------------------
__global__ void norm_kernel(const float* z1, const float* z2,
                            u16* zn1, u16* zn2, float* d12) {
    const int row = blockIdx.x;
    const int t = threadIdx.x;           // 256 threads
    const float* r1 = z1 + (size_t)row * DD;
    const float* r2 = z2 + (size_t)row * DD;
    float a0 = r1[t], a1 = r1[t + 256];
    float b0 = r2[t], b1 = r2[t + 256];
    float ss1 = a0 * a0 + a1 * a1;
    float ss2 = b0 * b0 + b1 * b1;
    #pragma unroll
    for (int m = 1; m < 64; m <<= 1) {
        ss1 += __shfl_xor(ss1, m);
        ss2 += __shfl_xor(ss2, m);
    }
    __shared__ float s1s[4], s2s[4], ds[4];
    const int wid = t >> 6, lane = t & 63;
    if (lane == 0) { s1s[wid] = ss1; s2s[wid] = ss2; }
    __syncthreads();
    const float n1 = s1s[0] + s1s[1] + s1s[2] + s1s[3];
    const float n2 = s2s[0] + s2s[1] + s2s[2] + s2s[3];
    const float inv1 = 1.0f / fmaxf(sqrtf(n1), 1e-12f);
    const float inv2 = 1.0f / fmaxf(sqrtf(n2), 1e-12f);
    const float u0 = a0 * inv1, u1 = a1 * inv1;
    const float v0 = b0 * inv2, v1 = b1 * inv2;
    zn1[(size_t)row * DD + t]       = f2bf(u0);
    zn1[(size_t)row * DD + t + 256] = f2bf(u1);
    zn2[(size_t)row * DD + t]       = f2bf(v0);
    zn2[(size_t)row * DD + t + 256] = f2bf(v1);
    float dp = u0 * v0 + u1 * v1;
    #pragma unroll
    for (int m = 1; m < 64; m <<= 1) dp += __shfl_xor(dp, m);
    if (lane == 0) ds[wid] = dp;
    __syncthreads();
    if (t == 0) d12[row] = ds[0] + ds[1] + ds[2] + ds[3];
}

// ---------------------------------------------------------------------------
// Kernel 2 (FAT, 512-thread blocks): score tiles (8 waves, 64x32 each ->
// 32 AGPR/wave, no spill) + (sparsify->sparse) 8-wave quads.
// grid 3640: g=bid/7, r=bid%7.
//   r<4  -> score id=g*4+r in [0,2080): id<1024 S12 full grid (p1 rows/p3
//           cols); else triangles S11 (mode0,p0) / S22 (mode2,p2).
//   r>=4 -> sparse sid=g*3+(r-4), active <1536; block = 16 consecutive rows
//           (one m), wave = 2 rows. (Round-12 verbatim — 244 µs stable best.)
// ---------------------------------------------------------------------------
__global__ __launch_bounds__(512, 3)
void fused_kernel(const u16* __restrict__ zn1, const u16* __restrict__ zn2,
                  const float* __restrict__ m0, const float* __restrict__ m1,
                  const float* __restrict__ m2, const float* __restrict__ m3,
                  const float* __restrict__ m4, const float* __restrict__ m5,
                  float* __restrict__ part, float* __restrict__ ms,
                  float* __restrict__ asum) {
    __shared__ u16 As[128 * 64];
    __shared__ u16 Bs[128 * 64];

    const int bid = blockIdx.x;
    const int tid = threadIdx.x;
    const int lane = tid & 63;

    const float C0 = 1.8033688011112042f;  // log2(e)/0.80
    const float C1 = 2.2542110013890054f;  // log2(e)/0.64
    const float C2 = 2.0037431123457825f;  // log2(e)/0.72

    const int g7 = bid / 7;
    const int r7 = bid - g7 * 7;

    if (r7 < 4) {
        // ================= SCORE PATH (8 waves, 64x32 per wave) =================
        const int id = g7 * 4 + r7;   // 0..2079
        int mode, by, bx;
        if (id < 1024) {
            mode = 1; by = id >> 5; bx = id & 31;
        } else {
            int k = id - 1024;
            mode = 0;
            if (k >= 528) { k -= 528; mode = 2; }
            int v = (int)((65.0f - sqrtf(4225.0f - 8.0f * (float)k)) * 0.5f);
            if (v < 0) v = 0; if (v > 31) v = 31;
            while (v < 31 && (v + 1) * 32 - ((v + 1) * v) / 2 <= k) v++;
            while (v > 0 && v * 32 - (v * (v - 1)) / 2 > k) v--;
            by = v;
            bx = by + (k - (by * 32 - (by * (by - 1)) / 2));
        }
        const int Ib = by * 128, Jb = bx * 128;
        const u16* Ag = (mode == 2) ? zn2 : zn1;
        const u16* Bg = (mode == 0) ? zn1 : zn2;
        const int p_row = mode;
        const int p_col = (mode == 1) ? 3 : mode;
        const bool do_cols = (mode == 1) || (bx != by);

        const int wid = tid >> 6;          // 0..7
        const int wm = wid >> 2;           // 0..1 (64-row half)
        const int wn = wid & 3;            // 0..3 (32-col quarter)
        const int quad = lane >> 4, lcol = lane & 15;

        f32x4 acc[4][2];
        #pragma unroll
        for (int a = 0; a < 4; a++)
            #pragma unroll
            for (int b = 0; b < 2; b++)
                acc[a][b] = (f32x4){0.f, 0.f, 0.f, 0.f};

        // 2 staging chunks per wave per buffer (16 chunks of 1 KB each)
        unsigned oA[2], oB[2];
        #pragma unroll
        for (int cc = 0; cc < 2; cc++) {
            const int ch = cc * 8 + wid;
            const int p = ch * 64 + lane;
            const int r = p >> 3;
            const int kb = (p & 7) ^ (r & 7);
            oA[cc] = (unsigned)((Ib + r) * DD + kb * 8);
            oB[cc] = (unsigned)((Jb + r) * DD + kb * 8);
        }

        for (int k0 = 0; k0 < DD; k0 += 64) {
            __syncthreads();
            #pragma unroll
            for (int cc = 0; cc < 2; cc++) {
                const unsigned lo = (unsigned)(cc * 8 + wid) * 1024u;
                __builtin_amdgcn_global_load_lds(AS_GLOBAL(Ag + oA[cc] + k0),
                                                 AS_LDS((char*)As + lo), 16, 0, 0);
                __builtin_amdgcn_global_load_lds(AS_GLOBAL(Bg + oB[cc] + k0),
                                                 AS_LDS((char*)Bs + lo), 16, 0, 0);
            }
            __syncthreads();
            #pragma unroll
            for (int kk = 0; kk < 64; kk += 32) {
                const int kbb = (kk >> 3) + quad;
                bf16x8 a[4], b[2];
                #pragma unroll
                for (int i = 0; i < 4; i++) {
                    const int ra = wm * 64 + i * 16 + lcol;
                    a[i] = *(const bf16x8*)&As[ra * 64 + ((kbb ^ (ra & 7)) * 8)];
                }
                #pragma unroll
                for (int i = 0; i < 2; i++) {
                    const int rb = wn * 32 + i * 16 + lcol;
                    b[i] = *(const bf16x8*)&Bs[rb * 64 + ((kbb ^ (rb & 7)) * 8)];
                }
                #pragma unroll
                for (int mi = 0; mi < 4; mi++)
                    #pragma unroll
                    for (int ni = 0; ni < 2; ni++)
                        acc[mi][ni] = __builtin_amdgcn_mfma_f32_16x16x32_bf16(a[mi], b[ni], acc[mi][ni], 0, 0, 0);
            }
        }

        // epilogue reuses As: sRow[4][3][128] (1536 f) + sCol[2][3][128] (768 f)
        __syncthreads();
        float* eb = (float*)As;
        float* sRow = eb;
        float* sCol = eb + 1536;

        float colacc[3][2];
        #pragma unroll
        for (int t = 0; t < 3; t++)
            #pragma unroll
            for (int ni = 0; ni < 2; ni++) colacc[t][ni] = 0.f;

        #pragma unroll
        for (int mi = 0; mi < 4; mi++) {
            #pragma unroll
            for (int reg = 0; reg < 4; reg++) {
                float p0 = 0.f, p1 = 0.f, p2 = 0.f;
                #pragma unroll
                for (int ni = 0; ni < 2; ni++) {
                    const float s = acc[mi][ni][reg];
                    const float e0 = __builtin_amdgcn_exp2f(s * C0);
                    const float e1 = __builtin_amdgcn_exp2f(s * C1);
                    const float e2 = __builtin_amdgcn_exp2f(s * C2);
                    p0 += e0; p1 += e1; p2 += e2;
                    colacc[0][ni] += e0; colacc[1][ni] += e1; colacc[2][ni] += e2;
                }
                #pragma unroll
                for (int msk = 1; msk < 16; msk <<= 1) {
                    p0 += __shfl_xor(p0, msk);
                    p1 += __shfl_xor(p1, msk);
                    p2 += __shfl_xor(p2, msk);
                }
                if (lcol == 0) {
                    const int r = wm * 64 + mi * 16 + quad * 4 + reg;
                    sRow[(wn * 3 + 0) * 128 + r] = p0;
                    sRow[(wn * 3 + 1) * 128 + r] = p1;
                    sRow[(wn * 3 + 2) * 128 + r] = p2;
                }
            }
        }
        #pragma unroll
        for (int t = 0; t < 3; t++) {
            #pragma unroll
            for (int ni = 0; ni < 2; ni++) {
                float v = colacc[t][ni];
                v += __shfl_xor(v, 16); v += __shfl_xor(v, 32);
                if (quad == 0) sCol[(wm * 3 + t) * 128 + wn * 32 + ni * 16 + lcol] = v;
            }
        }
        __syncthreads();
        if (tid < 128) {
            const int i = Ib + tid;
            #pragma unroll
            for (int t = 0; t < 3; t++) {
                const float v = sRow[(0 * 3 + t) * 128 + tid] + sRow[(1 * 3 + t) * 128 + tid]
                              + sRow[(2 * 3 + t) * 128 + tid] + sRow[(3 * 3 + t) * 128 + tid];
                part[(((size_t)p_row * 3 + t) * 32 + bx) * NR + i] = v;
            }
        } else if (tid < 256 && do_cols) {
            const int c = tid - 128;
            const int j = Jb + c;
            #pragma unroll
            for (int t = 0; t < 3; t++) {
                const float v = sCol[(0 * 3 + t) * 128 + c] + sCol[(1 * 3 + t) * 128 + c];
                part[(((size_t)p_col * 3 + t) * 32 + by) * NR + j] = v;
            }
        }
    } else {
        // ===== SPARSIFY + SPARSE PATH (8 waves x 2 rows; no barrier) =====
        const int sid = g7 * 3 + (r7 - 4);     // [0, 1560)
        if (sid >= 1536) return;
        const int widx = tid >> 6;             // 0..7
        const int grp = lane >> 4;
        const int l = lane & 15;
        const int wbase = sid * 16 + widx * 2; // even, block spans 16 rows, one m
        const int m = wbase >> 12;
        const int i0 = wbase & (NR - 1);

        const float* M = (m == 0) ? m0 : (m == 1) ? m1 : (m == 2) ? m2
                       : (m == 3) ? m3 : (m == 4) ? m4 : m5;
        const float4* p0 = (const float4*)(M + (size_t)i0 * NR) + lane;
        const float4* p1 = (const float4*)(M + (size_t)(i0 + 1) * NR) + lane;
        unsigned long long mask0 = 0ull, mask1 = 0ull;
        #pragma unroll
        for (int t = 0; t < 16; t++) {
            const float4 va = p0[t * 64];
            const float4 vb = p1[t * 64];
            mask0 |= (unsigned long long)((va.x != 0.f ? 1u : 0u)
                   | (va.y != 0.f ? 2u : 0u)
                   | (va.z != 0.f ? 4u : 0u)
                   | (va.w != 0.f ? 8u : 0u)) << (t * 4);
            mask1 |= (unsigned long long)((vb.x != 0.f ? 1u : 0u)
                   | (vb.y != 0.f ? 2u : 0u)
                   | (vb.z != 0.f ? 4u : 0u)
                   | (vb.w != 0.f ? 8u : 0u)) << (t * 4);
        }
        const int n0 = __popcll(mask0), n1 = __popcll(mask1);
        int off0 = n0, off1 = n1;
        #pragma unroll
        for (int d = 1; d < 64; d <<= 1) {
            const int t0 = __shfl_up(off0, d);
            const int t1 = __shfl_up(off1, d);
            if (lane >= d) { off0 += t0; off1 += t1; }
        }
        const int total0 = __shfl(off0, 63), total1 = __shfl(off1, 63);
        int* lidx0 = ((int*)As) + widx * 128;
        int* lidx1 = lidx0 + 64;
        int pos = off0 - n0;
        unsigned long long mm = mask0;
        while (mm) {
            const int b = __ffsll(mm) - 1;
            mm &= mm - 1;
            if (pos < CAP) lidx0[pos] = ((b >> 2) * 64 + lane) * 4 + (b & 3);
            pos++;
        }
        pos = off1 - n1;
        mm = mask1;
        while (mm) {
            const int b = __ffsll(mm) - 1;
            mm &= mm - 1;
            if (pos < CAP) lidx1[pos] = ((b >> 2) * 64 + lane) * 4 + (b & 3);
            pos++;
        }
        if (lane == 63) {
            asum[(size_t)m * NR + i0]     = (float)total0;
            asum[(size_t)m * NR + i0 + 1] = (float)total1;
        }
        const int cnt0 = min(total0, CAP), cnt1 = min(total1, CAP);
        // wave-private LDS: compiler inserts lgkmcnt before these reads
        const int jreg0 = lidx0[lane];
        const int jreg1 = lidx1[lane];

        int nslot; int slot[3]; float coef[3];
        switch (m) {
            case 0: nslot = 2; slot[0] = 0; coef[0] = C0; slot[1] = 3; coef[1] = C1; break;
            case 1: nslot = 2; slot[0] = 1; coef[0] = C0; slot[1] = 4; coef[1] = C2; break;
            case 2: nslot = 1; slot[0] = 2; coef[0] = C0; break;
            case 3: nslot = 1; slot[0] = 0; coef[0] = C0; break;
            case 4: nslot = 1; slot[0] = 1; coef[0] = C0; break;
            default: nslot = 3; slot[0] = 2; coef[0] = C0; slot[1] = 3; coef[1] = C1;
                     slot[2] = 4; coef[2] = C2; break;
        }

        const u16* A = (m < 3) ? zn1 : zn2;

        for (int rr = 0; rr < 2; rr++) {
            const int i = i0 + rr;
            const int cnt = rr ? cnt1 : cnt0;
            const int jreg = rr ? jreg1 : jreg0;

            unsigned au[16];
            {
                const uint4* ap = (const uint4*)(A + (size_t)i * DD) + l * 4;
                #pragma unroll
                for (int t = 0; t < 4; t++) {
                    const uint4 r = ap[t];
                    au[t * 4 + 0] = r.x; au[t * 4 + 1] = r.y;
                    au[t * 4 + 2] = r.z; au[t * 4 + 3] = r.w;
                }
            }

            float acc[3][2] = {{0.f, 0.f}, {0.f, 0.f}, {0.f, 0.f}};

            for (int q0 = 0; q0 < cnt; q0 += 4) {
                const int q = q0 + grp;
                const bool valid = q < cnt;
                const int j = __shfl(jreg, valid ? q : 0);

                const uint4* pj1 = (const uint4*)(zn1 + (size_t)j * DD) + l * 4;
                const uint4* pj2 = (const uint4*)(zn2 + (size_t)j * DD) + l * 4;
                uint4 r1[4], r2[4];
                #pragma unroll
                for (int t = 0; t < 4; t++) { r1[t] = pj1[t]; r2[t] = pj2[t]; }

                float s10 = 0.f, s11 = 0.f, s20 = 0.f, s21 = 0.f;
                #pragma unroll
                for (int t = 0; t < 4; t++) {
                    const unsigned* u1 = (const unsigned*)&r1[t];
                    const unsigned* u2 = (const unsigned*)&r2[t];
                    #pragma unroll
                    for (int qd = 0; qd < 4; qd++) {
                        const unsigned aw = au[t * 4 + qd];
                        const float alo = blo(aw), ahi = bhi(aw);
                        s10 += alo * blo(u1[qd]); s11 += ahi * bhi(u1[qd]);
                        s20 += alo * blo(u2[qd]); s21 += ahi * bhi(u2[qd]);
                    }
                }
                float d1 = s10 + s11, d2 = s20 + s21;
                #pragma unroll
                for (int msk = 1; msk < 16; msk <<= 1) {
                    d1 += __shfl_xor(d1, msk);
                    d2 += __shfl_xor(d2, msk);
                }
                const float e1 = (m < 3) ? d1 : d2;
                const float e2 = (m < 3) ? d2 : d1;
                if (valid) {
                    for (int s = 0; s < nslot; s++) {
                        acc[s][0] += __builtin_amdgcn_exp2f(e1 * coef[s]);
                        acc[s][1] += __builtin_amdgcn_exp2f(e2 * coef[s]);
                    }
                }
            }

            #pragma unroll
            for (int s = 0; s < 3; s++) {
                #pragma unroll
                for (int h = 0; h < 2; h++) {
                    float v = acc[s][h];
                    v += __shfl_xor(v, 16);
                    v += __shfl_xor(v, 32);
                    acc[s][h] = v;
                }
            }
            if (lane == 0) {
                const int pb = (m < 3) ? 0 : 2;
                for (int s = 0; s < nslot; s++) {
                    ms[((pb)     * 5 + slot[s]) * NR + i] = acc[s][0];
                    ms[((pb + 1) * 5 + slot[s]) * NR + i] = acc[s][1];
                }
            }
        }
    }
}

// ---------------------------------------------------------------------------
// Kernel 3: reduce partials over the 32 slots -> rs[(p*3+tau)*NR + i]
// (192 blocks — wide enough to be BW-bound; folding this into finalize1
//  regressed r14 by ~80 µs from 16-block latency serialization.)
// ---------------------------------------------------------------------------
__global__ __launch_bounds__(256)
void reduce_kernel(const float* __restrict__ part, float* __restrict__ rs) {
    const int g = blockIdx.x * 256 + threadIdx.x;
    const int pt = g >> 12;
    const int i = g & (NR - 1);
    const float* base = part + ((size_t)pt * 32) * NR + i;
    float s = 0.f;
    #pragma unroll
    for (int k = 0; k < 32; k++) s += base[(size_t)k * NR];
    rs[(size_t)pt * NR + i] = s;
}

// ---------------------------------------------------------------------------
// Kernel 4a: per-row loss terms, block-reduced -> pout[16][13]
// ---------------------------------------------------------------------------
__global__ __launch_bounds__(256)
void finalize1_kernel(const float* __restrict__ rs, const float* __restrict__ ms,
                      const float* __restrict__ asum, const float* __restrict__ d12,
                      float* __restrict__ pout) {
    const int t = threadIdx.x;
    const int i = blockIdx.x * 256 + t;
    const int tA[5] = {0, 0, 0, 1, 2};
    const int kA[5] = {0, 1, 2, 3, 4};
    const int aA[5] = {0, 1, 2, 0, 1};
    const int aB[5] = {3, 4, 5, 5, 5};
    const float it[3] = {1.25f, 1.5625f, 1.3888888888888888f};
    const float e1t[3] = {expf(1.25f), expf(1.5625f), expf(1.3888888888888888f)};

    const float d = d12[i];
    float ed[3];
    ed[0] = __expf(d * it[0]); ed[1] = __expf(d * it[1]); ed[2] = __expf(d * it[2]);
    float R[4][3], M[4][5], A6[6];
    #pragma unroll
    for (int p = 0; p < 4; p++) {
        #pragma unroll
        for (int tt = 0; tt < 3; tt++) R[p][tt] = rs[(p * 3 + tt) * NR + i];
        #pragma unroll
        for (int k = 0; k < 5; k++) M[p][k] = ms[(p * 5 + k) * NR + i];
    }
    #pragma unroll
    for (int a = 0; a < 6; a++) A6[a] = asum[a * NR + i];

    float vals[13];
    #pragma unroll
    for (int c = 0; c < 5; c++) {
        const int tt = tA[c], k = kA[c];
        float pos = ed[tt] + M[0][k] + M[1][k];
        float den = R[0][tt] + R[1][tt] - e1t[tt];
        float cnt = 2.f * A6[aA[c]] + 1.f;
        vals[c] = __logf(pos / den) / cnt;
        pos = ed[tt] + M[2][k] + M[3][k];
        den = R[2][tt] + R[3][tt] - e1t[tt];
        cnt = 2.f * A6[aB[c]] + 1.f;
        vals[5 + c] = __logf(pos / den) / cnt;
    }
    vals[10] = A6[0]; vals[11] = A6[1]; vals[12] = A6[2];

    __shared__ float red[256];
    for (int q = 0; q < 13; q++) {
        red[t] = vals[q];
        __syncthreads();
        for (int s = 128; s > 0; s >>= 1) {
            if (t < s) red[t] += red[t + s];
            __syncthreads();
        }
        if (t == 0) pout[blockIdx.x * 13 + q] = red[0];
        __syncthreads();
    }
}

// ---------------------------------------------------------------------------
// Kernel 4b: combine the 16 partials -> final scalar
// ---------------------------------------------------------------------------
__global__ void finalize2_kernel(const float* pout, float* out) {
    if (threadIdx.x == 0) {
        float tot[13];
        #pragma unroll
        for (int q = 0; q < 13; q++) tot[q] = 0.f;
        for (int b = 0; b < 16; b++)
            #pragma unroll
            for (int q = 0; q < 13; q++) tot[q] += pout[b * 13 + q];
        float Ac[5], Bc[5];
        #pragma unroll
        for (int c = 0; c < 5; c++) {
            Ac[c] = -tot[c] / (float)NR;
            Bc[c] = -tot[5 + c] / (float)NR;
        }
        const float ALPHA = 0.55f, BETA = 0.4f;
        const float Lc  = ALPHA * Ac[0] + BETA * Bc[0];
        const float Lm  = ALPHA * Ac[1] + BETA * Bc[1];
        const float Lf  = ALPHA * Ac[2] + BETA * Bc[2];
        const float Lcf = ALPHA * Ac[3] + BETA * Bc[3];
        const float Lmf = ALPHA * Ac[4] + BETA * Bc[4];
        const float scs = tot[10], sms = tot[11], sfs = tot[12];
        const float tot_info = scs + sms + sfs + 1e-8f;
        out[0] = (scs * Lc + sms * Lm + sfs * Lf) / tot_info + 0.2f * (Lcf + Lmf);
    }
}

extern "C" void kernel_launch(void* const* d_in, const int* in_sizes, int n_in,
                              void* d_out, int out_size, void* d_ws, size_t ws_size,
                              hipStream_t stream) {
    const float* z1  = (const float*)d_in[0];
    const float* z2  = (const float*)d_in[1];
    const float* ac  = (const float*)d_in[2];
    const float* am  = (const float*)d_in[3];
    const float* af  = (const float*)d_in[4];
    const float* aca = (const float*)d_in[5];
    const float* ama = (const float*)d_in[6];
    const float* afa = (const float*)d_in[7];

    float* ws   = (float*)d_ws;
    float* rs   = ws;                            // 12*NR
    float* ms   = rs + 12 * NR;                  // 20*NR
    float* asum = ms + 20 * NR;                  // 6*NR
    float* d12  = asum + 6 * NR;                 // NR
    u16* zn1 = (u16*)(d12 + NR);                 // NR*DD bf16
    u16* zn2 = zn1 + (size_t)NR * DD;
    float* part = (float*)(zn2 + (size_t)NR * DD);   // 12*32*NR
    float* pout = part + (size_t)12 * 32 * NR;       // 16*13

    norm_kernel<<<NR, 256, 0, stream>>>(z1, z2, zn1, zn2, d12);
    fused_kernel<<<3640, 512, 0, stream>>>(zn1, zn2, ac, am, af, aca, ama, afa,
                                           part, ms, asum);
    reduce_kernel<<<12 * NR / 256, 256, 0, stream>>>(part, rs);
    finalize1_kernel<<<16, 256, 0, stream>>>(rs, ms, asum, d12, pout);
    finalize2_kernel<<<1, 64, 0, stream>>>(pout, (float*)d_out);
}